// Round 17
// baseline (1952.733 us; speedup 1.0000x reference)
//
#include <hip/hip_runtime.h>

#define NB 128
#define NN 512
#define NODES (NB * NN)
#define NLEVELS 32

typedef __attribute__((ext_vector_type(8))) short short8;
typedef __attribute__((ext_vector_type(4))) short short4v;
typedef __attribute__((ext_vector_type(4))) float f32x4;
typedef unsigned int u32;

__device__ __forceinline__ float bf2f(short s) {
    union { u32 u; float f; } v;
    v.u = ((u32)(unsigned short)s) << 16;
    return v.f;
}
__device__ __forceinline__ short f2bf(float f) {
    union { u32 u; float f; } v;
    v.f = f;
    u32 u = v.u + 0x7FFFu + ((v.u >> 16) & 1u);  // RNE
    return (short)(u >> 16);
}
// clamp that also sanitizes NaN (AMD v_min/v_max return the non-NaN operand)
__device__ __forceinline__ float fclamp(float x, float lo, float hi) {
    return fminf(fmaxf(x, lo), hi);
}
__device__ __forceinline__ float fsig(float x) {
    return __builtin_amdgcn_rcpf(1.f + __builtin_amdgcn_exp2f(-1.44269504f * x));
}
__device__ __forceinline__ float ftanh(float x) {
    return 1.f - 2.f * __builtin_amdgcn_rcpf(1.f + __builtin_amdgcn_exp2f(2.88539008f * x));
}
#define MFMA16(a, b, c) __builtin_amdgcn_mfma_f32_16x16x32_bf16((a), (b), (c), 0, 0, 0)

// async global->LDS 16B (per-lane global source, wave-uniform LDS dest + lane*16)
__device__ __forceinline__ void gl16(const void* g, void* l) {
    __builtin_amdgcn_global_load_lds(
        (const __attribute__((address_space(1))) unsigned int*)g,
        (__attribute__((address_space(3))) unsigned int*)l,
        16, 0, 0);
}

// ---------------------------------------------------------------------------
// conv_emb_kernel: fp32 emb (node order) -> bf16 emb_lvl (LEVEL-SORTED order)
// via pos_g.
// ---------------------------------------------------------------------------
__global__ __launch_bounds__(256) void conv_emb_kernel(
    const float* __restrict__ src, const u32* __restrict__ pos_g,
    short* __restrict__ dst)
{
    int i = blockIdx.x * 256 + threadIdx.x;
    const int stride = gridDim.x * 256;
    for (; i < NODES * 64; i += stride) {
        const int node = i >> 6;
        const int o = (i & 63) << 3;      // element offset (8 floats)
        const u32 dr = pos_g[node];
        const float* s = src + ((size_t)node << 9) + o;
        short8 v;
#pragma unroll
        for (int j = 0; j < 8; j++) v[j] = f2bf(s[j]);
        *(short8*)((char*)dst + ((size_t)dr << 10) + ((size_t)o << 1)) = v;
    }
}

// ---------------------------------------------------------------------------
// Weight pre-pack (unchanged): images in exact LDS staging byte order.
// Blin img: [cg(8)][kc(16)][24576 B]; kc<8 from ul, kc>=8 from ur.
// ---------------------------------------------------------------------------
__global__ __launch_bounds__(256) void wpack_lin_kernel(
    const float* __restrict__ ul, const float* __restrict__ ur,
    short* __restrict__ img)
{
    int gid = blockIdx.x * 256 + threadIdx.x;              // 196608 groups
    const int stride = gridDim.x * 256;
    for (; gid < 196608; gid += stride) {
        const int cgkc = gid / 1536;          // img block
        const int d = (gid - cgkc * 1536) << 4;            // dest byte in img
        const int cg = cgkc >> 4, kc = cgkc & 15;
        const int u = d ^ (((d >> 7) & 7) << 4);           // inverse swizzle
        const int p = u >> 7;                              // B row 0..191
        const int koff = u & 127;                          // byte in 128B k-chunk
        const int row = ((p >> 6) << 9) + (cg << 6) + (p & 63);   // g*512 + h
        const float* src = (kc < 8 ? ul : ur) + (size_t)row * 512
                         + ((kc & 7) << 6) + (koff >> 1);
        short8 o;
#pragma unroll
        for (int i = 0; i < 8; i++) o[i] = f2bf(src[i]);
        *(short8*)((char*)img + (size_t)cgkc * 24576 + d) = o;
    }
}
// Pool imgs: [s(24)][ch(8)][8192 B] for wl and wr each.
__global__ __launch_bounds__(256) void wpack_pool_kernel(
    const float* __restrict__ wl, const float* __restrict__ wr,
    short* __restrict__ imgL, short* __restrict__ imgR)
{
    int gid = blockIdx.x * 256 + threadIdx.x;              // 2 x 98304 groups
    const int stride = gridDim.x * 256;
    for (; gid < 196608; gid += stride) {
        const int tensor = gid >= 98304;
        const int g2 = gid - tensor * 98304;
        const int sc = g2 / 512;                           // img block
        const int d = (g2 - sc * 512) << 4;                // dest byte
        const int s = sc >> 3, ch = sc & 7;
        const int slot = d >> 10;
        const int l = (d >> 4) & 63;
        const int col = (slot << 3) + (l >> 3);
        const int eoff = ((l & 7) ^ (col & 7)) << 3;       // elem offset in 64
        const float* src = (tensor ? wr : wl)
                         + (size_t)(s * 64 + col) * 512 + (ch << 6) + eoff;
        short8 o;
#pragma unroll
        for (int i = 0; i < 8; i++) o[i] = f2bf(src[i]);
        short* dst = tensor ? imgR : imgL;
        *(short8*)((char*)dst + (size_t)sc * 8192 + d) = o;
    }
}

// ---------------------------------------------------------------------------
// Setup (parallel): zero -> depth (pointer doubling, 1 block/tree) -> scan ->
// scatter. Emits list, pos_g[node]=level-pos, plist[pos]=parent level-pos.
// ---------------------------------------------------------------------------
__global__ __launch_bounds__(256) void zero_kernel(int* __restrict__ counts)
{
    const int i = blockIdx.x * 256 + threadIdx.x;
    if (i < 520) counts[i] = 0;
}

__global__ __launch_bounds__(256) void depth_kernel(
    const int* __restrict__ conn,
    unsigned char* __restrict__ lvl_g,  // [NODES]
    int* __restrict__ counts)           // [520]
{
    __shared__ short anc[NN];
    __shared__ short dep[NN];
    __shared__ int hist[520];
    const int b = blockIdx.x;
    const int tid = threadIdx.x;

    for (int i = tid; i < 520; i += 256) hist[i] = 0;
    for (int i = tid; i < NN; i += 256) {
        anc[i] = (i == 0) ? (short)0 : (short)conn[b * NN + i];  // par < i
        dep[i] = (i == 0) ? (short)0 : (short)1;
    }
    __syncthreads();
    for (int it = 0; it < 9; it++) {
        const int i0 = tid, i1 = tid + 256;
        const short a0 = anc[i0], d0 = dep[i0];
        const short a1 = anc[i1], d1 = dep[i1];
        const short da0 = dep[a0], aa0 = anc[a0];
        const short da1 = dep[a1], aa1 = anc[a1];
        __syncthreads();
        dep[i0] = (short)(d0 + da0); anc[i0] = aa0;
        dep[i1] = (short)(d1 + da1); anc[i1] = aa1;
        __syncthreads();
    }
    for (int i = tid; i < NN; i += 256) {
        const unsigned char d = (unsigned char)dep[i];
        lvl_g[b * NN + i] = d;
        atomicAdd(&hist[d], 1);
    }
    __syncthreads();
    for (int i = tid; i < 520; i += 256)
        if (hist[i]) atomicAdd(&counts[i], hist[i]);
}

__global__ __launch_bounds__(256) void scan_kernel(
    const int* __restrict__ counts,
    int* __restrict__ offs,
    int* __restrict__ cursor)
{
    __shared__ int c[520];
    __shared__ int o[520];
    const int tid = threadIdx.x;
    for (int i = tid; i < 520; i += 256) c[i] = counts[i];
    __syncthreads();
    if (tid == 0) {
        int acc = 0;
        for (int l = 0; l < 520; l++) { o[l] = acc; acc += c[l]; }
    }
    __syncthreads();
    for (int i = tid; i < 520; i += 256) {
        offs[i] = o[i];
        cursor[i] = o[i];
    }
}

__global__ __launch_bounds__(256) void scatter_kernel(
    const int* __restrict__ conn,
    const unsigned char* __restrict__ lvl_g,
    int* __restrict__ cursor,
    u32* __restrict__ list,
    u32* __restrict__ pos_g,   // [NODES] node -> level position
    u32* __restrict__ plist)   // [NODES] level position -> parent's level pos
{
    __shared__ int hist[520];
    __shared__ int base_s[520];
    __shared__ short rank_s[NN];
    __shared__ int pos_s[NN];
    const int b = blockIdx.x;
    const int tid = threadIdx.x;

    for (int i = tid; i < 520; i += 256) hist[i] = 0;
    __syncthreads();
    for (int i = tid; i < NN; i += 256) {
        const int l = lvl_g[b * NN + i];
        rank_s[i] = (short)atomicAdd(&hist[l], 1);
    }
    __syncthreads();
    for (int i = tid; i < 520; i += 256) {
        const int c = hist[i];
        base_s[i] = c ? atomicAdd(&cursor[i], c) : 0;
    }
    __syncthreads();
    for (int i = tid; i < NN; i += 256) {
        const int l = lvl_g[b * NN + i];
        pos_s[i] = base_s[l] + rank_s[i];
    }
    __syncthreads();
    for (int i = tid; i < NN; i += 256) {
        const int par = (i == 0) ? 0 : conn[b * NN + i];
        const int pos = pos_s[i];
        list[pos] = ((u32)b << 18) | ((u32)i << 9) | (u32)par;
        plist[pos] = (u32)pos_s[par];   // root: self, unused at lvl 0
        pos_g[b * NN + i] = (u32)pos;
    }
}

// ---------------------------------------------------------------------------
// pool_kernel v3 (lin-v6 pattern): A (Ae/Ah) in REGISTERS with unconditional
// clamped one-chunk-ahead prefetch; B (Bl/Br) via 32 KB LDS double buffer
// (4 gl16/wave/chunk). launch_bounds(256,2) -> VGPR headroom for prefetch
// (R12's failure: bounds(256,4) capped VGPR AND A was not prefetched).
// LDS 32KB -> 4 blocks/CU; grid 960. Output pooled2[mr*24+gp]. lvl > 0 only.
// ---------------------------------------------------------------------------
__global__ __launch_bounds__(256, 2) void pool_kernel(
    const int lvl,
    const short* __restrict__ emb_lvl,
    const short* __restrict__ imgL,   // packed wl images [s][ch][8192B]
    const short* __restrict__ imgR,   // packed wr images
    const short* __restrict__ h_lvl,
    const int* __restrict__ offs,
    const u32* __restrict__ plist,
    float* __restrict__ pooled2)      // [m][24]
{
    const int base = offs[lvl];
    const int M = offs[lvl + 1] - base;
    if (M <= 0) return;
    const int nt = (M + 63) >> 6;     // 64-row tiles

    const int s = blockIdx.x % 24;    // gp slice
    const int rb = blockIdx.x / 24;
    const int nb = gridDim.x / 24;
    if (rb >= nt) return;

    // [buf]: Bl 8KB | Br 8KB   (A never touches LDS)
    __shared__ __attribute__((aligned(16))) char lds[2][16384];

    const int tid = threadIdx.x;
    const int l = tid & 63;
    const int w = tid >> 6;           // wave 0..3
    const int q = l >> 4;
    const int ln = l & 15;

    // packed B bases: per chunk ch, slot (2w+cc): contiguous 1 KB
    const char* bL = (const char*)imgL + (size_t)s * 65536 + (l << 4);
    const char* bR = (const char*)imgR + (size_t)s * 65536 + (l << 4);

    for (int tm = rb; tm < nt; tm += nb) {
        const int m0 = tm << 6;
        // per-lane A row pointers (q*16 folded in); pad rows clamp to M-1
        const char *pAe, *pAh;
        {
            int r = m0 + (w << 4) + ln; if (r > M - 1) r = M - 1;
            const int qo = q << 4;
            pAe = (const char*)emb_lvl + ((size_t)(base + r) << 10) + qo;
            pAh = (const char*)h_lvl + ((size_t)plist[base + r] << 10) + qo;
        }

        f32x4 accL[4], accR[4];
#pragma unroll
        for (int jj = 0; jj < 4; jj++) {
            accL[jj] = {0.f, 0.f, 0.f, 0.f};
            accR[jj] = {0.f, 0.f, 0.f, 0.f};
        }

        // prologue: stage B chunk 0 (4 gl16/wave); preload A chunk 0 regs
        {
            char* L = lds[0];
#pragma unroll
            for (int cc = 0; cc < 2; cc++) {
                const int slt = (2 * w + cc) << 10;
                gl16(bL + slt, L + slt);
                gl16(bR + slt, L + 8192 + slt);
            }
        }
        short8 ae0 = *(const short8*)(pAe);        // chunk0 kf0
        short8 ae1 = *(const short8*)(pAe + 64);   // chunk0 kf1
        short8 ah0 = *(const short8*)(pAh);
        short8 ah1 = *(const short8*)(pAh + 64);
        __syncthreads();

        for (int c = 0; c < 8; c++) {
            // UNCONDITIONAL clamped A-prefetch of chunk kn (last: reload cur)
            const int kn = (c + 1 < 8) ? c + 1 : c;
            const int cbn = kn << 7;
            short8 ne0 = *(const short8*)(pAe + cbn);
            short8 ne1 = *(const short8*)(pAe + cbn + 64);
            short8 nh0 = *(const short8*)(pAh + cbn);
            short8 nh1 = *(const short8*)(pAh + cbn + 64);
            // stage B chunk c+1 into the other buffer
            if (c + 1 < 8) {
                char* L = lds[(c + 1) & 1];
                const size_t ib = (size_t)(c + 1) << 13;  // 8KB per chunk
#pragma unroll
                for (int cc = 0; cc < 2; cc++) {
                    const int slt = (2 * w + cc) << 10;
                    gl16(bL + ib + slt, L + slt);
                    gl16(bR + ib + slt, L + 8192 + slt);
                }
            }
            // compute chunk c: A from current regs, B from LDS
            const char* L = lds[c & 1];
#pragma unroll
            for (int kf = 0; kf < 2; kf++) {
                const short8 ae = kf ? ae1 : ae0;
                const short8 ah = kf ? ah1 : ah0;
#pragma unroll
                for (int jj = 0; jj < 4; jj++) {
                    const int bbyte = (((jj << 4) + ln) << 7) + (kf << 6) + (q << 4);
                    const int bswz = bbyte ^ ((ln & 7) << 4);
                    const short8 bl = *(const short8*)(L + bswz);
                    const short8 br = *(const short8*)(L + 8192 + bswz);
                    accL[jj] = MFMA16(ae, bl, accL[jj]);
                    accR[jj] = MFMA16(ah, br, accR[jj]);
                }
            }
            __syncthreads();   // B(c+1) + A-prefetch landed; buf c&1 free
            ae0 = ne0; ae1 = ne1; ah0 = nh0; ah1 = nh1;  // unconditional rotate
        }

#pragma unroll
        for (int reg = 0; reg < 4; reg++) {
            float v = accL[0][reg] * accR[0][reg] + accL[1][reg] * accR[1][reg]
                    + accL[2][reg] * accR[2][reg] + accL[3][reg] * accR[3][reg];
            v += __shfl_xor(v, 1, 64);
            v += __shfl_xor(v, 2, 64);
            v += __shfl_xor(v, 4, 64);
            v += __shfl_xor(v, 8, 64);
            if (ln == 0) {
                const int mr = m0 + (w << 4) + (q << 2) + reg;
                if (mr < M) pooled2[(size_t)mr * 24 + s] = v;
            }
        }
    }
}

// ---------------------------------------------------------------------------
// gemm_lin_kernel v6 (unchanged from R16): register double-buffered A
// (spill-proofed: bounds(256,2) + unconditional clamped prefetch), B via
// 2x24KB LDS dbuf, XCD-grouped tiles, fused LSTM epilogue.
// ---------------------------------------------------------------------------
__global__ __launch_bounds__(256, 2) void gemm_lin_kernel(
    const int lvl,
    const short* __restrict__ emb_lvl,
    const short* __restrict__ Blin,   // packed [8][16][24576B]
    const float* __restrict__ wo,
    const float* __restrict__ bias,
    const int* __restrict__ offs,
    const u32* __restrict__ list,
    const u32* __restrict__ plist,
    const float* __restrict__ pooled2,
    float* __restrict__ h_out,    // d_out fp32 (node-ordered)
    short* __restrict__ h_lvl,    // ws bf16 level-sorted h
    short* __restrict__ c_lvl)    // ws bf16 level-sorted c
{
    const int base = offs[lvl];
    const int M = offs[lvl + 1] - base;
    if (M <= 0) return;
    const int nt = (M + 127) >> 7;           // 128-row tiles
    const int nkc = (lvl > 0) ? 16 : 8;      // 64-k chunks (E:0..7, H:8..15)

    // [buf][ B-panel 24576 B ]  (A never touches LDS)
    __shared__ __attribute__((aligned(16))) char lds[2][24576];

    const int tid = threadIdx.x;
    const int lane = tid & 63;
    const int w = tid >> 6;                  // wave 0..3
    const int q = lane >> 4;
    const int ln = lane & 15;
    const int x = blockIdx.x & 7;            // XCD partition
    const int jb = blockIdx.x >> 3;          // 0..95
    const int cg = jb & 7;                   // h-col group
    const int tslot = jb >> 3;               // 0..11
    const int swzc = (ln & 7) << 4;          // B read-side swizzle constant

    // packed B base for this cg: cg stride = 16 chunks x 24576 B = 393216 B
    const char* pB = (const char*)Blin + (size_t)cg * 393216 + (lane << 4);

    const int wrow0 = w << 5;                // wave's 32 rows

    for (int tm = x + (tslot << 3); tm < nt; tm += 96) {
        const int m0 = tm << 7;
        // per-lane A row pointers: E rows contiguous; H rows via plist.
        const char *pE0, *pE1, *pH0, *pH1;
        {
            int r0 = m0 + wrow0 + ln;      if (r0 > M - 1) r0 = M - 1;
            int r1 = m0 + wrow0 + 16 + ln; if (r1 > M - 1) r1 = M - 1;
            const int qo = q << 4;
            pE0 = (const char*)emb_lvl + ((size_t)(base + r0) << 10) + qo;
            pE1 = (const char*)emb_lvl + ((size_t)(base + r1) << 10) + qo;
            pH0 = (const char*)h_lvl + ((size_t)plist[base + r0] << 10) + qo;
            pH1 = (const char*)h_lvl + ((size_t)plist[base + r1] << 10) + qo;
        }

        f32x4 acc[2][12];
#pragma unroll
        for (int ms = 0; ms < 2; ms++)
#pragma unroll
            for (int j = 0; j < 12; j++)
                acc[ms][j] = {0.f, 0.f, 0.f, 0.f};

        // prologue: stage B chunk 0; preload A chunk 0 into current regs
        {
            char* LB = lds[0];
#pragma unroll
            for (int c = 0; c < 6; c++)
                gl16(pB + ((w * 6 + c) << 10), LB + ((w * 6 + c) << 10));
        }
        short8 c00 = *(const short8*)(pE0);        // A0 ks0
        short8 c01 = *(const short8*)(pE0 + 64);   // A0 ks1
        short8 c10 = *(const short8*)(pE1);        // A1 ks0
        short8 c11 = *(const short8*)(pE1 + 64);   // A1 ks1
        __syncthreads();

        for (int kc = 0; kc < nkc; kc++) {
            // UNCONDITIONAL clamped A-prefetch of chunk kn
            const int kn = (kc + 1 < nkc) ? kc + 1 : kc;
            const char* r0 = (kn < 8) ? pE0 : pH0;
            const char* r1 = (kn < 8) ? pE1 : pH1;
            const int cbn = (kn & 7) << 7;
            short8 n00 = *(const short8*)(r0 + cbn);
            short8 n01 = *(const short8*)(r0 + cbn + 64);
            short8 n10 = *(const short8*)(r1 + cbn);
            short8 n11 = *(const short8*)(r1 + cbn + 64);
            // stage B chunk kc+1 into the other buffer
            if (kc + 1 < nkc) {
                const size_t ib = (size_t)(kc + 1) * 24576;
                char* LB = lds[(kc + 1) & 1];
#pragma unroll
                for (int c = 0; c < 6; c++)
                    gl16(pB + ib + ((w * 6 + c) << 10), LB + ((w * 6 + c) << 10));
            }
            // compute chunk kc: A from current regs, B from LDS
            const char* LB = lds[kc & 1];
#pragma unroll
            for (int ks = 0; ks < 2; ks++) {
                const short8 af0 = ks ? c01 : c00;
                const short8 af1 = ks ? c11 : c10;
                const int kb = (ks << 6) + (q << 4);
#pragma unroll
                for (int j = 0; j < 12; j++) {
                    const short8 bf = *(const short8*)(LB + ((((j * 16 + ln) << 7) + kb) ^ swzc));
                    acc[0][j] = MFMA16(af0, bf, acc[0][j]);
                    acc[1][j] = MFMA16(af1, bf, acc[1][j]);
                }
            }
            __syncthreads();   // B(kc+1) + A-prefetch landed; buf kc&1 free
            c00 = n00; c01 = n01; c10 = n10; c11 = n11;  // unconditional rotate
        }

        // fused epilogue: lane holds all 3 gates of its (row, h)
#pragma unroll
        for (int ms = 0; ms < 2; ms++) {
#pragma unroll
            for (int reg = 0; reg < 4; reg++) {
                const int mr = m0 + wrow0 + (ms << 4) + (q << 2) + reg;
                if (mr >= M) continue;       // pad rows never write
                const u32 pk = list[base + mr];
                const int bb = pk >> 18, tt = (pk >> 9) & 511;
                const u32 ppos = plist[base + mr];
                const float* pr = pooled2 + (size_t)mr * 24;
                const size_t orow = ((size_t)((bb << 9) | tt)) << 9;  // h_out
                const size_t srow = ((size_t)(base + mr)) << 9;       // c/h_lvl
                const size_t prow = ((size_t)ppos) << 9;
#pragma unroll
                for (int jh = 0; jh < 4; jh++) {
                    const int h = (cg << 6) + (jh << 4) + ln;
                    float v[3];
#pragma unroll
                    for (int g = 0; g < 3; g++) {
                        float xg = acc[ms][(g << 2) + jh][reg] + bias[(g << 9) + h];
                        if (lvl > 0) {
                            const float* wop = wo + ((size_t)((g << 9) + h) << 3);
                            float sdot = 0.f;
#pragma unroll
                            for (int p2 = 0; p2 < 8; p2++)
                                sdot += pr[(g << 3) + p2] * wop[p2];
                            xg += sdot;
                        }
                        // clamp + NaN-sanitize (min/max drop NaN on AMD)
                        v[g] = fclamp(xg, -30.f, 30.f);
                    }
                    const float fg = fsig(v[0]);
                    const float og = fsig(v[1]);
                    const float zg = ftanh(v[2]);
                    float pc = 0.f;
                    if (lvl > 0) {
                        pc = bf2f(c_lvl[prow + h]);
                        pc = fclamp(pc, -1.f, 1.f);  // |c|<=1 by induction
                    }
                    const float cc = pc * fg + (1.f - fg) * zg;
                    const float hh = og * ftanh(cc);
                    c_lvl[srow + h] = f2bf(cc);
                    h_lvl[srow + h] = f2bf(hh);
                    h_out[orow + h] = hh;
                }
            }
        }
    }
}

extern "C" void kernel_launch(void* const* d_in, const int* in_sizes, int n_in,
                              void* d_out, int out_size, void* d_ws, size_t ws_size,
                              hipStream_t stream) {
    const float* emb  = (const float*)d_in[0];  // (B,N,IN) fp32
    const int*   conn = (const int*)d_in[1];    // (B,N) int32
    // d_in[2] node_mask: all ones, unused
    const float* wl   = (const float*)d_in[3];  // (3,8,64,512) fp32
    const float* wr   = (const float*)d_in[4];  // (3,8,64,512) fp32
    const float* wo   = (const float*)d_in[5];  // (3,512,8)    fp32
    const float* ul   = (const float*)d_in[6];  // (3,512,512)  fp32
    const float* ur   = (const float*)d_in[7];  // (3,512,512)  fp32
    const float* bias = (const float*)d_in[8];  // (3,512)      fp32

    char* ws = (char*)d_ws;
    int* offs   = (int*)ws;          // 520
    int* counts = offs + 520;        // 520
    int* cursor = counts + 520;      // 520
    unsigned char* lvl_g = (unsigned char*)(ws + 8192);   // 64 KiB
    u32* list  = (u32*)(ws + 73728);                      // 256 KiB
    u32* pos_g = (u32*)(ws + 335872);                     // 256 KiB
    u32* plist = (u32*)(ws + 598016);                     // 256 KiB -> 860160
    // packed weight images:
    short* Blin  = (short*)(ws + 860160);                 // 3,145,728 B
    short* PimgL = (short*)(ws + 860160 + 3145728);       // 1,572,864 B
    short* PimgR = (short*)(ws + 860160 + 4718592);       // 1,572,864 B (ends ~7.15 MiB)
    short* emb_lvl = (short*)(ws + (8u << 20));           // 64 MiB (level-sorted)
    short* h_lvl = (short*)(ws + (8u << 20) + 67108864u);
    short* c_lvl = (short*)(ws + (8u << 20) + 134217728u); // ends at 200 MiB
    float* pooled2 = (float*)(ws + 209715200ull);         // 6.3 MB (needs ws >= 216 MiB)

    float* h_out = (float*)d_out;

    // weight image packing (independent of tree)
    wpack_lin_kernel<<<dim3(768), dim3(256), 0, stream>>>(ul, ur, Blin);
    wpack_pool_kernel<<<dim3(768), dim3(256), 0, stream>>>(wl, wr, PimgL, PimgR);

    // parallel setup: zero -> depth -> scan -> scatter (pos_g/plist)
    zero_kernel<<<dim3(3), dim3(256), 0, stream>>>(counts);
    depth_kernel<<<dim3(NB), dim3(256), 0, stream>>>(conn, lvl_g, counts);
    scan_kernel<<<dim3(1), dim3(256), 0, stream>>>(counts, offs, cursor);
    scatter_kernel<<<dim3(NB), dim3(256), 0, stream>>>(conn, lvl_g, cursor,
                                                       list, pos_g, plist);
    // emb fp32 -> bf16, reordered into level-sorted layout (needs pos_g)
    conv_emb_kernel<<<dim3(2048), dim3(256), 0, stream>>>(emb, pos_g, emb_lvl);

    for (int l = 0; l < NLEVELS; l++) {
        if (l > 0)
            pool_kernel<<<dim3(960), dim3(256), 0, stream>>>(
                l, emb_lvl, PimgL, PimgR, h_lvl, offs, plist, pooled2);
        gemm_lin_kernel<<<dim3(768), dim3(256), 0, stream>>>(
            l, emb_lvl, Blin, wo, bias, offs, list, plist, pooled2,
            h_out, h_lvl, c_lvl);
    }
}

// Round 18
// 1758.620 us; speedup vs baseline: 1.1104x; 1.1104x over previous
//
#include <hip/hip_runtime.h>

#define NB 128
#define NN 512
#define NODES (NB * NN)
#define NLEVELS 32

typedef __attribute__((ext_vector_type(8))) short short8;
typedef __attribute__((ext_vector_type(4))) short short4v;
typedef __attribute__((ext_vector_type(4))) float f32x4;
typedef unsigned int u32;

__device__ __forceinline__ float bf2f(short s) {
    union { u32 u; float f; } v;
    v.u = ((u32)(unsigned short)s) << 16;
    return v.f;
}
__device__ __forceinline__ short f2bf(float f) {
    union { u32 u; float f; } v;
    v.f = f;
    u32 u = v.u + 0x7FFFu + ((v.u >> 16) & 1u);  // RNE
    return (short)(u >> 16);
}
// clamp that also sanitizes NaN (AMD v_min/v_max return the non-NaN operand)
__device__ __forceinline__ float fclamp(float x, float lo, float hi) {
    return fminf(fmaxf(x, lo), hi);
}
__device__ __forceinline__ float fsig(float x) {
    return __builtin_amdgcn_rcpf(1.f + __builtin_amdgcn_exp2f(-1.44269504f * x));
}
__device__ __forceinline__ float ftanh(float x) {
    return 1.f - 2.f * __builtin_amdgcn_rcpf(1.f + __builtin_amdgcn_exp2f(2.88539008f * x));
}
#define MFMA16(a, b, c) __builtin_amdgcn_mfma_f32_16x16x32_bf16((a), (b), (c), 0, 0, 0)

// async global->LDS 16B (per-lane global source, wave-uniform LDS dest + lane*16)
__device__ __forceinline__ void gl16(const void* g, void* l) {
    __builtin_amdgcn_global_load_lds(
        (const __attribute__((address_space(1))) unsigned int*)g,
        (__attribute__((address_space(3))) unsigned int*)l,
        16, 0, 0);
}

// T4 pipeline primitives (pool kernel)
#define WAIT_VMCNT(n) asm volatile("s_waitcnt vmcnt(" #n ")" ::: "memory")
#define PIPE_BAR()                                  \
    do {                                            \
        __builtin_amdgcn_sched_barrier(0);          \
        __builtin_amdgcn_s_barrier();               \
        __builtin_amdgcn_sched_barrier(0);          \
    } while (0)

// ---------------------------------------------------------------------------
// conv_emb_kernel: fp32 emb (node order) -> bf16 emb_lvl (LEVEL-SORTED order)
// via pos_g.
// ---------------------------------------------------------------------------
__global__ __launch_bounds__(256) void conv_emb_kernel(
    const float* __restrict__ src, const u32* __restrict__ pos_g,
    short* __restrict__ dst)
{
    int i = blockIdx.x * 256 + threadIdx.x;
    const int stride = gridDim.x * 256;
    for (; i < NODES * 64; i += stride) {
        const int node = i >> 6;
        const int o = (i & 63) << 3;      // element offset (8 floats)
        const u32 dr = pos_g[node];
        const float* s = src + ((size_t)node << 9) + o;
        short8 v;
#pragma unroll
        for (int j = 0; j < 8; j++) v[j] = f2bf(s[j]);
        *(short8*)((char*)dst + ((size_t)dr << 10) + ((size_t)o << 1)) = v;
    }
}

// ---------------------------------------------------------------------------
// Weight pre-pack (unchanged): images in exact LDS staging byte order.
// Blin img: [cg(8)][kc(16)][24576 B]; kc<8 from ul, kc>=8 from ur.
// ---------------------------------------------------------------------------
__global__ __launch_bounds__(256) void wpack_lin_kernel(
    const float* __restrict__ ul, const float* __restrict__ ur,
    short* __restrict__ img)
{
    int gid = blockIdx.x * 256 + threadIdx.x;              // 196608 groups
    const int stride = gridDim.x * 256;
    for (; gid < 196608; gid += stride) {
        const int cgkc = gid / 1536;          // img block
        const int d = (gid - cgkc * 1536) << 4;            // dest byte in img
        const int cg = cgkc >> 4, kc = cgkc & 15;
        const int u = d ^ (((d >> 7) & 7) << 4);           // inverse swizzle
        const int p = u >> 7;                              // B row 0..191
        const int koff = u & 127;                          // byte in 128B k-chunk
        const int row = ((p >> 6) << 9) + (cg << 6) + (p & 63);   // g*512 + h
        const float* src = (kc < 8 ? ul : ur) + (size_t)row * 512
                         + ((kc & 7) << 6) + (koff >> 1);
        short8 o;
#pragma unroll
        for (int i = 0; i < 8; i++) o[i] = f2bf(src[i]);
        *(short8*)((char*)img + (size_t)cgkc * 24576 + d) = o;
    }
}
// Pool imgs: [s(24)][ch(8)][8192 B] for wl and wr each.
__global__ __launch_bounds__(256) void wpack_pool_kernel(
    const float* __restrict__ wl, const float* __restrict__ wr,
    short* __restrict__ imgL, short* __restrict__ imgR)
{
    int gid = blockIdx.x * 256 + threadIdx.x;              // 2 x 98304 groups
    const int stride = gridDim.x * 256;
    for (; gid < 196608; gid += stride) {
        const int tensor = gid >= 98304;
        const int g2 = gid - tensor * 98304;
        const int sc = g2 / 512;                           // img block
        const int d = (g2 - sc * 512) << 4;                // dest byte
        const int s = sc >> 3, ch = sc & 7;
        const int slot = d >> 10;
        const int l = (d >> 4) & 63;
        const int col = (slot << 3) + (l >> 3);
        const int eoff = ((l & 7) ^ (col & 7)) << 3;       // elem offset in 64
        const float* src = (tensor ? wr : wl)
                         + (size_t)(s * 64 + col) * 512 + (ch << 6) + eoff;
        short8 o;
#pragma unroll
        for (int i = 0; i < 8; i++) o[i] = f2bf(src[i]);
        short* dst = tensor ? imgR : imgL;
        *(short8*)((char*)dst + (size_t)sc * 8192 + d) = o;
    }
}

// ---------------------------------------------------------------------------
// Setup (parallel): zero -> depth (pointer doubling, 1 block/tree) -> scan ->
// scatter. Emits list, pos_g[node]=level-pos, plist[pos]=parent level-pos.
// ---------------------------------------------------------------------------
__global__ __launch_bounds__(256) void zero_kernel(int* __restrict__ counts)
{
    const int i = blockIdx.x * 256 + threadIdx.x;
    if (i < 520) counts[i] = 0;
}

__global__ __launch_bounds__(256) void depth_kernel(
    const int* __restrict__ conn,
    unsigned char* __restrict__ lvl_g,  // [NODES]
    int* __restrict__ counts)           // [520]
{
    __shared__ short anc[NN];
    __shared__ short dep[NN];
    __shared__ int hist[520];
    const int b = blockIdx.x;
    const int tid = threadIdx.x;

    for (int i = tid; i < 520; i += 256) hist[i] = 0;
    for (int i = tid; i < NN; i += 256) {
        anc[i] = (i == 0) ? (short)0 : (short)conn[b * NN + i];  // par < i
        dep[i] = (i == 0) ? (short)0 : (short)1;
    }
    __syncthreads();
    for (int it = 0; it < 9; it++) {
        const int i0 = tid, i1 = tid + 256;
        const short a0 = anc[i0], d0 = dep[i0];
        const short a1 = anc[i1], d1 = dep[i1];
        const short da0 = dep[a0], aa0 = anc[a0];
        const short da1 = dep[a1], aa1 = anc[a1];
        __syncthreads();
        dep[i0] = (short)(d0 + da0); anc[i0] = aa0;
        dep[i1] = (short)(d1 + da1); anc[i1] = aa1;
        __syncthreads();
    }
    for (int i = tid; i < NN; i += 256) {
        const unsigned char d = (unsigned char)dep[i];
        lvl_g[b * NN + i] = d;
        atomicAdd(&hist[d], 1);
    }
    __syncthreads();
    for (int i = tid; i < 520; i += 256)
        if (hist[i]) atomicAdd(&counts[i], hist[i]);
}

__global__ __launch_bounds__(256) void scan_kernel(
    const int* __restrict__ counts,
    int* __restrict__ offs,
    int* __restrict__ cursor)
{
    __shared__ int c[520];
    __shared__ int o[520];
    const int tid = threadIdx.x;
    for (int i = tid; i < 520; i += 256) c[i] = counts[i];
    __syncthreads();
    if (tid == 0) {
        int acc = 0;
        for (int l = 0; l < 520; l++) { o[l] = acc; acc += c[l]; }
    }
    __syncthreads();
    for (int i = tid; i < 520; i += 256) {
        offs[i] = o[i];
        cursor[i] = o[i];
    }
}

__global__ __launch_bounds__(256) void scatter_kernel(
    const int* __restrict__ conn,
    const unsigned char* __restrict__ lvl_g,
    int* __restrict__ cursor,
    u32* __restrict__ list,
    u32* __restrict__ pos_g,   // [NODES] node -> level position
    u32* __restrict__ plist)   // [NODES] level position -> parent's level pos
{
    __shared__ int hist[520];
    __shared__ int base_s[520];
    __shared__ short rank_s[NN];
    __shared__ int pos_s[NN];
    const int b = blockIdx.x;
    const int tid = threadIdx.x;

    for (int i = tid; i < 520; i += 256) hist[i] = 0;
    __syncthreads();
    for (int i = tid; i < NN; i += 256) {
        const int l = lvl_g[b * NN + i];
        rank_s[i] = (short)atomicAdd(&hist[l], 1);
    }
    __syncthreads();
    for (int i = tid; i < 520; i += 256) {
        const int c = hist[i];
        base_s[i] = c ? atomicAdd(&cursor[i], c) : 0;
    }
    __syncthreads();
    for (int i = tid; i < NN; i += 256) {
        const int l = lvl_g[b * NN + i];
        pos_s[i] = base_s[l] + rank_s[i];
    }
    __syncthreads();
    for (int i = tid; i < NN; i += 256) {
        const int par = (i == 0) ? 0 : conn[b * NN + i];
        const int pos = pos_s[i];
        list[pos] = ((u32)b << 18) | ((u32)i << 9) | (u32)par;
        plist[pos] = (u32)pos_s[par];   // root: self, unused at lvl 0
        pos_g[b * NN + i] = (u32)pos;
    }
}

// ---------------------------------------------------------------------------
// pool_kernel (REVERTED to R16-best version): level-sorted state, LDS-staged
// A+B with counted-vmcnt pipeline (8 loads in flight across barriers -- the
// deeper pipeline that both rewrites lost), grid 480, 2 blocks/CU.
// Output pooled2[mr*24+gp]. lvl > 0 only.
// ---------------------------------------------------------------------------
__global__ __launch_bounds__(256, 2) void pool_kernel(
    const int lvl,
    const short* __restrict__ emb_lvl,
    const short* __restrict__ imgL,   // packed wl images [s][ch][8192B]
    const short* __restrict__ imgR,   // packed wr images
    const short* __restrict__ h_lvl,
    const int* __restrict__ offs,
    const u32* __restrict__ plist,
    float* __restrict__ pooled2)      // [m][24]
{
    const int base = offs[lvl];
    const int M = offs[lvl + 1] - base;
    if (M <= 0) return;
    const int nt = (M + 63) >> 6;     // 64-row tiles

    const int s = blockIdx.x % 24;    // gp slice
    const int rb = blockIdx.x / 24;
    const int nb = gridDim.x / 24;
    if (rb >= nt) return;

    // [buf]: Ae 8KB | Ah 8KB | Bl 8KB | Br 8KB
    __shared__ __attribute__((aligned(16))) char lds[2][32768];

    const int tid = threadIdx.x;
    const int l = tid & 63;
    const int w = tid >> 6;           // wave 0..3
    const int q = l >> 4;
    const int ln = l & 15;

    // packed B bases: per chunk ch, slot (2w+cc): contiguous 1 KB
    const char* bL = (const char*)imgL + (size_t)s * 65536 + (l << 4);
    const char* bR = (const char*)imgR + (size_t)s * 65536 + (l << 4);

    for (int tm = rb; tm < nt; tm += nb) {
        const int m0 = tm << 6;
        const char* pAe[2];
        const char* pAh[2];
#pragma unroll
        for (int cc = 0; cc < 2; cc++) {
            const int row = ((2 * w + cc) << 3) + (l >> 3);
            const int koff = ((l & 7) ^ (row & 7)) << 4;
            int mr = m0 + row; if (mr > M - 1) mr = M - 1;   // pad rows dup M-1
            pAe[cc] = (const char*)emb_lvl + ((size_t)(base + mr) << 10) + koff;
            pAh[cc] = (const char*)h_lvl + ((size_t)plist[base + mr] << 10) + koff;
        }

        f32x4 accL[4], accR[4];
#pragma unroll
        for (int jj = 0; jj < 4; jj++) {
            accL[jj] = {0.f, 0.f, 0.f, 0.f};
            accR[jj] = {0.f, 0.f, 0.f, 0.f};
        }

        // prologue: stage chunk 0 into buf 0 (8 gl16/wave)
        {
            char* L = lds[0];
#pragma unroll
            for (int cc = 0; cc < 2; cc++) {
                const int slt = (2 * w + cc) << 10;
                gl16(pAe[cc], L + slt);
                gl16(pAh[cc], L + 8192 + slt);
                gl16(bL + slt, L + 16384 + slt);
                gl16(bR + slt, L + 24576 + slt);
            }
        }

        for (int c = 0; c < 8; c++) {
            if (c < 7) {
                // stage chunk c+1 (8 gl16/wave), then wait only for chunk c
                char* L = lds[(c + 1) & 1];
                const int cb = (c + 1) << 7;     // 128B per 64-k chunk (A only)
                const size_t ib = (size_t)(c + 1) << 13;  // 8KB per chunk (B imgs)
#pragma unroll
                for (int cc = 0; cc < 2; cc++) {
                    const int slt = (2 * w + cc) << 10;
                    gl16(pAe[cc] + cb, L + slt);
                    gl16(pAh[cc] + cb, L + 8192 + slt);
                    gl16(bL + ib + slt, L + 16384 + slt);
                    gl16(bR + ib + slt, L + 24576 + slt);
                }
                WAIT_VMCNT(8);
            } else {
                WAIT_VMCNT(0);
            }
            PIPE_BAR();   // all waves' chunk-c loads landed
            const char* L = lds[c & 1];
#pragma unroll
            for (int kf = 0; kf < 2; kf++) {
                const int abyte = (((w << 4) + ln) << 7) + (kf << 6) + (q << 4);
                const int aswz = abyte ^ ((ln & 7) << 4);
                const short8 ae = *(const short8*)(L + aswz);
                const short8 ah = *(const short8*)(L + 8192 + aswz);
#pragma unroll
                for (int jj = 0; jj < 4; jj++) {
                    const int bbyte = (((jj << 4) + ln) << 7) + (kf << 6) + (q << 4);
                    const int bswz = bbyte ^ ((ln & 7) << 4);
                    const short8 bl = *(const short8*)(L + 16384 + bswz);
                    const short8 br = *(const short8*)(L + 24576 + bswz);
                    accL[jj] = MFMA16(ae, bl, accL[jj]);
                    accR[jj] = MFMA16(ah, br, accR[jj]);
                }
            }
            PIPE_BAR();   // all waves done reading buf c&1 before it's restaged
        }

#pragma unroll
        for (int reg = 0; reg < 4; reg++) {
            float v = accL[0][reg] * accR[0][reg] + accL[1][reg] * accR[1][reg]
                    + accL[2][reg] * accR[2][reg] + accL[3][reg] * accR[3][reg];
            v += __shfl_xor(v, 1, 64);
            v += __shfl_xor(v, 2, 64);
            v += __shfl_xor(v, 4, 64);
            v += __shfl_xor(v, 8, 64);
            if (ln == 0) {
                const int mr = m0 + (w << 4) + (q << 2) + reg;
                if (mr < M) pooled2[(size_t)mr * 24 + s] = v;
            }
        }
    }
}

// ---------------------------------------------------------------------------
// gemm_lin_kernel v6 (unchanged, R16-best): register double-buffered A
// (spill-proofed: bounds(256,2) + unconditional clamped prefetch), B via
// 2x24KB LDS dbuf, XCD-grouped tiles, fused LSTM epilogue.
// ---------------------------------------------------------------------------
__global__ __launch_bounds__(256, 2) void gemm_lin_kernel(
    const int lvl,
    const short* __restrict__ emb_lvl,
    const short* __restrict__ Blin,   // packed [8][16][24576B]
    const float* __restrict__ wo,
    const float* __restrict__ bias,
    const int* __restrict__ offs,
    const u32* __restrict__ list,
    const u32* __restrict__ plist,
    const float* __restrict__ pooled2,
    float* __restrict__ h_out,    // d_out fp32 (node-ordered)
    short* __restrict__ h_lvl,    // ws bf16 level-sorted h
    short* __restrict__ c_lvl)    // ws bf16 level-sorted c
{
    const int base = offs[lvl];
    const int M = offs[lvl + 1] - base;
    if (M <= 0) return;
    const int nt = (M + 127) >> 7;           // 128-row tiles
    const int nkc = (lvl > 0) ? 16 : 8;      // 64-k chunks (E:0..7, H:8..15)

    // [buf][ B-panel 24576 B ]  (A never touches LDS)
    __shared__ __attribute__((aligned(16))) char lds[2][24576];

    const int tid = threadIdx.x;
    const int lane = tid & 63;
    const int w = tid >> 6;                  // wave 0..3
    const int q = lane >> 4;
    const int ln = lane & 15;
    const int x = blockIdx.x & 7;            // XCD partition
    const int jb = blockIdx.x >> 3;          // 0..95
    const int cg = jb & 7;                   // h-col group
    const int tslot = jb >> 3;               // 0..11
    const int swzc = (ln & 7) << 4;          // B read-side swizzle constant

    // packed B base for this cg: cg stride = 16 chunks x 24576 B = 393216 B
    const char* pB = (const char*)Blin + (size_t)cg * 393216 + (lane << 4);

    const int wrow0 = w << 5;                // wave's 32 rows

    for (int tm = x + (tslot << 3); tm < nt; tm += 96) {
        const int m0 = tm << 7;
        // per-lane A row pointers: E rows contiguous; H rows via plist.
        const char *pE0, *pE1, *pH0, *pH1;
        {
            int r0 = m0 + wrow0 + ln;      if (r0 > M - 1) r0 = M - 1;
            int r1 = m0 + wrow0 + 16 + ln; if (r1 > M - 1) r1 = M - 1;
            const int qo = q << 4;
            pE0 = (const char*)emb_lvl + ((size_t)(base + r0) << 10) + qo;
            pE1 = (const char*)emb_lvl + ((size_t)(base + r1) << 10) + qo;
            pH0 = (const char*)h_lvl + ((size_t)plist[base + r0] << 10) + qo;
            pH1 = (const char*)h_lvl + ((size_t)plist[base + r1] << 10) + qo;
        }

        f32x4 acc[2][12];
#pragma unroll
        for (int ms = 0; ms < 2; ms++)
#pragma unroll
            for (int j = 0; j < 12; j++)
                acc[ms][j] = {0.f, 0.f, 0.f, 0.f};

        // prologue: stage B chunk 0; preload A chunk 0 into current regs
        {
            char* LB = lds[0];
#pragma unroll
            for (int c = 0; c < 6; c++)
                gl16(pB + ((w * 6 + c) << 10), LB + ((w * 6 + c) << 10));
        }
        short8 c00 = *(const short8*)(pE0);        // A0 ks0
        short8 c01 = *(const short8*)(pE0 + 64);   // A0 ks1
        short8 c10 = *(const short8*)(pE1);        // A1 ks0
        short8 c11 = *(const short8*)(pE1 + 64);   // A1 ks1
        __syncthreads();

        for (int kc = 0; kc < nkc; kc++) {
            // UNCONDITIONAL clamped A-prefetch of chunk kn
            const int kn = (kc + 1 < nkc) ? kc + 1 : kc;
            const char* r0 = (kn < 8) ? pE0 : pH0;
            const char* r1 = (kn < 8) ? pE1 : pH1;
            const int cbn = (kn & 7) << 7;
            short8 n00 = *(const short8*)(r0 + cbn);
            short8 n01 = *(const short8*)(r0 + cbn + 64);
            short8 n10 = *(const short8*)(r1 + cbn);
            short8 n11 = *(const short8*)(r1 + cbn + 64);
            // stage B chunk kc+1 into the other buffer
            if (kc + 1 < nkc) {
                const size_t ib = (size_t)(kc + 1) * 24576;
                char* LB = lds[(kc + 1) & 1];
#pragma unroll
                for (int c = 0; c < 6; c++)
                    gl16(pB + ib + ((w * 6 + c) << 10), LB + ((w * 6 + c) << 10));
            }
            // compute chunk kc: A from current regs, B from LDS
            const char* LB = lds[kc & 1];
#pragma unroll
            for (int ks = 0; ks < 2; ks++) {
                const short8 af0 = ks ? c01 : c00;
                const short8 af1 = ks ? c11 : c10;
                const int kb = (ks << 6) + (q << 4);
#pragma unroll
                for (int j = 0; j < 12; j++) {
                    const short8 bf = *(const short8*)(LB + ((((j * 16 + ln) << 7) + kb) ^ swzc));
                    acc[0][j] = MFMA16(af0, bf, acc[0][j]);
                    acc[1][j] = MFMA16(af1, bf, acc[1][j]);
                }
            }
            __syncthreads();   // B(kc+1) + A-prefetch landed; buf kc&1 free
            c00 = n00; c01 = n01; c10 = n10; c11 = n11;  // unconditional rotate
        }

        // fused epilogue: lane holds all 3 gates of its (row, h)
#pragma unroll
        for (int ms = 0; ms < 2; ms++) {
#pragma unroll
            for (int reg = 0; reg < 4; reg++) {
                const int mr = m0 + wrow0 + (ms << 4) + (q << 2) + reg;
                if (mr >= M) continue;       // pad rows never write
                const u32 pk = list[base + mr];
                const int bb = pk >> 18, tt = (pk >> 9) & 511;
                const u32 ppos = plist[base + mr];
                const float* pr = pooled2 + (size_t)mr * 24;
                const size_t orow = ((size_t)((bb << 9) | tt)) << 9;  // h_out
                const size_t srow = ((size_t)(base + mr)) << 9;       // c/h_lvl
                const size_t prow = ((size_t)ppos) << 9;
#pragma unroll
                for (int jh = 0; jh < 4; jh++) {
                    const int h = (cg << 6) + (jh << 4) + ln;
                    float v[3];
#pragma unroll
                    for (int g = 0; g < 3; g++) {
                        float xg = acc[ms][(g << 2) + jh][reg] + bias[(g << 9) + h];
                        if (lvl > 0) {
                            const float* wop = wo + ((size_t)((g << 9) + h) << 3);
                            float sdot = 0.f;
#pragma unroll
                            for (int p2 = 0; p2 < 8; p2++)
                                sdot += pr[(g << 3) + p2] * wop[p2];
                            xg += sdot;
                        }
                        // clamp + NaN-sanitize (min/max drop NaN on AMD)
                        v[g] = fclamp(xg, -30.f, 30.f);
                    }
                    const float fg = fsig(v[0]);
                    const float og = fsig(v[1]);
                    const float zg = ftanh(v[2]);
                    float pc = 0.f;
                    if (lvl > 0) {
                        pc = bf2f(c_lvl[prow + h]);
                        pc = fclamp(pc, -1.f, 1.f);  // |c|<=1 by induction
                    }
                    const float cc = pc * fg + (1.f - fg) * zg;
                    const float hh = og * ftanh(cc);
                    c_lvl[srow + h] = f2bf(cc);
                    h_lvl[srow + h] = f2bf(hh);
                    h_out[orow + h] = hh;
                }
            }
        }
    }
}

extern "C" void kernel_launch(void* const* d_in, const int* in_sizes, int n_in,
                              void* d_out, int out_size, void* d_ws, size_t ws_size,
                              hipStream_t stream) {
    const float* emb  = (const float*)d_in[0];  // (B,N,IN) fp32
    const int*   conn = (const int*)d_in[1];    // (B,N) int32
    // d_in[2] node_mask: all ones, unused
    const float* wl   = (const float*)d_in[3];  // (3,8,64,512) fp32
    const float* wr   = (const float*)d_in[4];  // (3,8,64,512) fp32
    const float* wo   = (const float*)d_in[5];  // (3,512,8)    fp32
    const float* ul   = (const float*)d_in[6];  // (3,512,512)  fp32
    const float* ur   = (const float*)d_in[7];  // (3,512,512)  fp32
    const float* bias = (const float*)d_in[8];  // (3,512)      fp32

    char* ws = (char*)d_ws;
    int* offs   = (int*)ws;          // 520
    int* counts = offs + 520;        // 520
    int* cursor = counts + 520;      // 520
    unsigned char* lvl_g = (unsigned char*)(ws + 8192);   // 64 KiB
    u32* list  = (u32*)(ws + 73728);                      // 256 KiB
    u32* pos_g = (u32*)(ws + 335872);                     // 256 KiB
    u32* plist = (u32*)(ws + 598016);                     // 256 KiB -> 860160
    // packed weight images:
    short* Blin  = (short*)(ws + 860160);                 // 3,145,728 B
    short* PimgL = (short*)(ws + 860160 + 3145728);       // 1,572,864 B
    short* PimgR = (short*)(ws + 860160 + 4718592);       // 1,572,864 B (ends ~7.15 MiB)
    short* emb_lvl = (short*)(ws + (8u << 20));           // 64 MiB (level-sorted)
    short* h_lvl = (short*)(ws + (8u << 20) + 67108864u);
    short* c_lvl = (short*)(ws + (8u << 20) + 134217728u); // ends at 200 MiB
    float* pooled2 = (float*)(ws + 209715200ull);         // 6.3 MB (needs ws >= 216 MiB)

    float* h_out = (float*)d_out;

    // weight image packing (independent of tree)
    wpack_lin_kernel<<<dim3(768), dim3(256), 0, stream>>>(ul, ur, Blin);
    wpack_pool_kernel<<<dim3(768), dim3(256), 0, stream>>>(wl, wr, PimgL, PimgR);

    // parallel setup: zero -> depth -> scan -> scatter (pos_g/plist)
    zero_kernel<<<dim3(3), dim3(256), 0, stream>>>(counts);
    depth_kernel<<<dim3(NB), dim3(256), 0, stream>>>(conn, lvl_g, counts);
    scan_kernel<<<dim3(1), dim3(256), 0, stream>>>(counts, offs, cursor);
    scatter_kernel<<<dim3(NB), dim3(256), 0, stream>>>(conn, lvl_g, cursor,
                                                       list, pos_g, plist);
    // emb fp32 -> bf16, reordered into level-sorted layout (needs pos_g)
    conv_emb_kernel<<<dim3(2048), dim3(256), 0, stream>>>(emb, pos_g, emb_lvl);

    for (int l = 0; l < NLEVELS; l++) {
        if (l > 0)
            pool_kernel<<<dim3(480), dim3(256), 0, stream>>>(
                l, emb_lvl, PimgL, PimgR, h_lvl, offs, plist, pooled2);
        gemm_lin_kernel<<<dim3(768), dim3(256), 0, stream>>>(
            l, emb_lvl, Blin, wo, bias, offs, list, plist, pooled2,
            h_out, h_lvl, c_lvl);
    }
}